// Round 7
// baseline (288.130 us; speedup 1.0000x reference)
//
#include <hip/hip_runtime.h>

typedef __bf16 bf16x8 __attribute__((ext_vector_type(8)));
typedef float f32x4 __attribute__((ext_vector_type(4)));
typedef unsigned short us8 __attribute__((ext_vector_type(8)));

#define PI_F 3.14159265358979323846f

__device__ __forceinline__ unsigned short f2bf(float f) {
    unsigned u = __float_as_uint(f);
    u += 0x7FFFu + ((u >> 16) & 1u);   // RNE
    return (unsigned short)(u >> 16);
}
__device__ __forceinline__ float bf2f(unsigned short h) {
    return __uint_as_float(((unsigned)h) << 16);
}

__device__ __forceinline__ void async16(const void* g, void* l) {
    __builtin_amdgcn_global_load_lds(
        (const __attribute__((address_space(1))) unsigned int*)g,
        (__attribute__((address_space(3))) unsigned int*)l, 16, 0, 0);
}

// ---------------------------------------------------------------------------
// Merged weight prep.  Grid 5120:
//  bid <  4096: W1b[(k*8+h)*1024 + d] = bf16( W_proj[h,k,d] * cos(pi*f[h,k]) )
//               (block = quarter of row n = bid>>2; fully coalesced)
//  bid >= 4096: Wob[n*1024 + (k*8+h)] = bf16( out_W[n, h*128+k] )
//               via LDS row transpose: coalesced float4 read of Wo row,
//               padded LDS (+4/128) kills the 8-way h-stride conflict,
//               coalesced ushort4 write.  (r6 audit: old path was 64
//               segments/wave on the Wo read.)
__global__ __launch_bounds__(256) void prep_k(const float* __restrict__ W,
                                              const float* __restrict__ fr,
                                              const float* __restrict__ Wo,
                                              unsigned short* __restrict__ W1b,
                                              unsigned short* __restrict__ Wob) {
    int bid = blockIdx.x, t = threadIdx.x;
    if (bid < 4096) {
        int n = bid >> 2, d = (bid & 3) * 256 + t;
        int k = n >> 3, h = n & 7;
        float c = cosf(fr[h * 128 + k] * PI_F);
        W1b[n * 1024 + d] = f2bf(W[((h * 128 + k) << 10) + d] * c);
    } else {
        __shared__ float lds[1056];          // 1024 + 4-per-128 padding
        int n = bid - 4096;
        float4 v = ((const float4*)(Wo + (n << 10)))[t];
        int e = t * 4;
        *(float4*)&lds[e + (e >> 7) * 4] = v;
        __syncthreads();
        ushort4 o;
        unsigned short* op = (unsigned short*)&o;
#pragma unroll
        for (int j = 0; j < 4; ++j) {
            int dp = t * 4 + j;
            int h = dp & 7, k = dp >> 3;
            op[j] = f2bf(lds[h * 132 + k]);  // e=h*128+k -> padded h*132+k
        }
        ((ushort4*)(Wob + (n << 10)))[t] = o;
    }
}

// ---------------------------------------------------------------------------
// x -> bf16 cast + per-(b,d) partial column sums via PLAIN stores.
__global__ __launch_bounds__(256) void xbar_cast(const float* __restrict__ x,
                                                 unsigned short* __restrict__ xb,
                                                 float* __restrict__ part) {
    int bid = blockIdx.x;            // 1024
    int b = bid >> 8;
    int s0 = (bid & 255) * 16;
    int t = threadIdx.x;             // d4 index
    float a0 = 0.f, a1 = 0.f, a2 = 0.f, a3 = 0.f;
    for (int i = 0; i < 16; ++i) {
        long row = (long)b * 4096 + s0 + i;
        float4 v = ((const float4*)x)[row * 256 + t];
        a0 += v.x; a1 += v.y; a2 += v.z; a3 += v.w;
        ushort4 u;
        u.x = f2bf(v.x); u.y = f2bf(v.y); u.z = f2bf(v.z); u.w = f2bf(v.w);
        ((ushort4*)xb)[row * 256 + t] = u;
    }
    float4 p; p.x = a0; p.y = a1; p.z = a2; p.w = a3;
    ((float4*)part)[bid * 256 + t] = p;
}

// Reduce part[1024][1024] -> xbar[4][1024]. 32 blocks, fully coalesced.
__global__ __launch_bounds__(256) void xbar_r(const float* __restrict__ part,
                                              float* __restrict__ xbar) {
    __shared__ float sl[256];
    int blk = blockIdx.x;            // 32 = b*8 + dgrp
    int b = blk >> 3, dgrp = blk & 7;
    int t = threadIdx.x;
    int col = dgrp * 128 + (t & 127);
    int ih = t >> 7;
    float s = 0.f;
    for (int i = 0; i < 128; ++i) {
        int cb = b * 256 + ih * 128 + i;
        s += part[cb * 1024 + col];
    }
    sl[t] = s;
    __syncthreads();
    if (t < 128) xbar[b * 1024 + col] = sl[t] + sl[t + 128];
}

// ---------------------------------------------------------------------------
// summary[b,h,k] = (1/S) * dot(xbar[b,:], W_proj[h,k,:]) * cos(pi*freq[h,k])
__global__ __launch_bounds__(256) void summary_k(const float* __restrict__ xbar,
                                                 const float* __restrict__ W,
                                                 const float* __restrict__ fr,
                                                 float* __restrict__ summary) {
    int wave = (blockIdx.x * 256 + threadIdx.x) >> 6;   // 0..4095 = b*1024+h*128+k
    int lane = threadIdx.x & 63;
    int b = wave >> 10, hk = wave & 1023;
    int h = hk >> 7, k = hk & 127;
    const float* wrow = &W[(h * 128 + k) << 10];
    const float* xrow = &xbar[b << 10];
    float s = 0.f;
    for (int d = lane; d < 1024; d += 64) s += xrow[d] * wrow[d];
    for (int off = 32; off; off >>= 1) s += __shfl_down(s, off);
    if (lane == 0) {
        float c = cosf(fr[h * 128 + k] * PI_F);
        summary[wave] = s * c * (1.0f / 4096.0f);
    }
}

// ---------------------------------------------------------------------------
// pol -> normalize -> dots -> gelu MLP -> softplus -> impedance & coef.
// Single block but 1024 threads (16 waves TLP on the CU; r6 audit: the old
// 256-thread version was a serial-latency suspect) + float4 dot loads.
__global__ __launch_bounds__(1024) void imp_k(const float* __restrict__ summary,
                                              const float* __restrict__ pol_W,
                                              const float* __restrict__ pol_b,
                                              const float* __restrict__ imp_W1,
                                              const float* __restrict__ imp_b1,
                                              const float* __restrict__ imp_W2,
                                              const float* __restrict__ imp_b2,
                                              float* __restrict__ coef_out,
                                              float* __restrict__ imp_out) {
    __shared__ float pol[4][8][32];
    __shared__ float rn[32];
    int t = threadIdx.x;
    {
        int b = t >> 8, h = (t >> 5) & 7, p = t & 31;
        const float4* srow = (const float4*)&summary[(b * 8 + h) * 128];
        const float4* wrow = (const float4*)&pol_W[(h * 32 + p) * 128];
        float acc = pol_b[h * 32 + p];
        for (int k = 0; k < 32; ++k) {
            float4 sv = srow[k], wv = wrow[k];
            acc += sv.x * wv.x + sv.y * wv.y + sv.z * wv.z + sv.w * wv.w;
        }
        pol[b][h][p] = tanhf(acc);
    }
    __syncthreads();
    if (t < 32) {
        int b = t >> 3, h = t & 7;
        float ss = 0.f;
        for (int p = 0; p < 32; ++p) { float v = pol[b][h][p]; ss += v * v; }
        rn[t] = 1.0f / fmaxf(sqrtf(ss), 1e-12f);
    }
    __syncthreads();
    if (t < 256) {
        int b = t >> 6, i = (t >> 3) & 7, j = t & 7;
        float d = 0.f;
        for (int p = 0; p < 32; ++p) d += pol[b][i][p] * pol[b][j][p];
        d *= rn[b * 8 + i] * rn[b * 8 + j];
        float s = imp_b2[0];
        for (int c = 0; c < 16; ++c) {
            float z = d * imp_W1[c] + imp_b1[c];
            float gl = 0.5f * z * (1.0f + erff(z * 0.70710678118654752f));
            s += gl * imp_W2[c];
        }
        float sp = fmaxf(s, 0.0f) + log1pf(expf(-fabsf(s)));   // softplus
        float impv = (i == j) ? 0.0f : sp;
        imp_out[t] = impv;
        coef_out[t] = (i == j) ? 0.0f : 0.1f / (1.0f + impv);
    }
}

// ---------------------------------------------------------------------------
// ===== 256x256 GEMM core: r6 frozen (ring-4, counted vmcnt, coalesced ======
// staging).  Measured r6: 49.0us, MfmaUtil 26.7%, conflicts 0 in K-loop.
// 703 TF = 83% of m248's 848 TF (best documented plain-HIP at 256sq/K=1024).
// ---------------------------------------------------------------------------
#define VMCNT(n) asm volatile("s_waitcnt vmcnt(" #n ")" ::: "memory")
#define SBAR() __builtin_amdgcn_s_barrier()

// XCD-contiguous swizzle for grid 256 (64 row-blocks x 4 col-blocks).
// Verified r1: FETCH 41 -> 24.8 MB.
__device__ __forceinline__ void swz256(int n, long& rowBase, long& colBase) {
    int xcd = n & 7, s = n >> 3;                 // s in 0..31
    rowBase = (long)(xcd * 8 + (s & 7)) * 256;
    colBase = (long)(s >> 3) * 256;
}

#define STG(sPtr, dPtr, koff, slot)                                          \
    async16((sPtr) + (koff), (dPtr) + (slot) * 16384);                       \
    async16((sPtr) + (koff) + 262144, (dPtr) + (slot) * 16384 + 8192);

// One phase: stage half p+2, counted wait, barrier, 12 reads + 32 MFMA.
#define PH(p, DO_ST, KOFF, VM)                                               \
    {                                                                        \
        if (DO_ST) {                                                         \
            STG(sA, stDstA, (KOFF), ((p) + 2) & 3)                           \
            STG(sB, stDstB, (KOFF), ((p) + 2) & 3)                           \
        }                                                                    \
        VM;                                                                  \
        SBAR();                                                              \
        const char* pA = rdA + ((p) & 3) * 16384;                            \
        const char* pB = rdB + ((p) & 3) * 16384;                            \
        bf16x8 af[4], bv[4];                                                 \
        _Pragma("unroll") for (int i_ = 0; i_ < 4; ++i_)                     \
            af[i_] = *(const bf16x8*)(pA + i_ * 1024);                       \
        _Pragma("unroll") for (int i_ = 0; i_ < 4; ++i_)                     \
            bv[i_] = *(const bf16x8*)(pB + i_ * 1024);                       \
        __builtin_amdgcn_s_setprio(1);                                       \
        _Pragma("unroll") for (int mi = 0; mi < 4; ++mi)                     \
            _Pragma("unroll") for (int ni = 0; ni < 4; ++ni)                 \
                acc[mi][ni] = __builtin_amdgcn_mfma_f32_16x16x32_bf16(       \
                    af[mi], bv[ni], acc[mi][ni], 0, 0, 0);                   \
        __builtin_amdgcn_s_setprio(0);                                       \
        _Pragma("unroll") for (int i_ = 0; i_ < 4; ++i_)                     \
            af[i_] = *(const bf16x8*)(pA + (4 + i_) * 1024);                 \
        __builtin_amdgcn_s_setprio(1);                                       \
        _Pragma("unroll") for (int mi = 0; mi < 4; ++mi)                     \
            _Pragma("unroll") for (int ni = 0; ni < 4; ++ni)                 \
                acc[4 + mi][ni] = __builtin_amdgcn_mfma_f32_16x16x32_bf16(   \
                    af[mi], bv[ni], acc[4 + mi][ni], 0, 0, 0);               \
        __builtin_amdgcn_s_setprio(0);                                       \
    }

__device__ __forceinline__ void gemm8_core(const char* gAB, const char* gBB,
                                           char* smem, const int t,
                                           f32x4 acc[8][4]) {
    const int l = t & 63, wid = t >> 6;
    const int wm = wid >> 2, wn = wid & 3;
    // COALESCED staging source: row = wid*16 + (l>>2) (4-lane groups share a
    // row -> one 64B segment), chunk = (l&3) ^ ((l>>3)&3) (read-swizzle fold).
    const long stOff =
        (long)((wid << 4) + (l >> 2)) * 2048 + (((l & 3) ^ ((l >> 3) & 3)) * 16);
    const char* sA = gAB + stOff;
    const char* sB = gBB + stOff;
    char* As = smem;                 // 4 slots x 16KB
    char* Bs = smem + 65536;         // 4 slots x 16KB
    char* stDstA = As + wid * 1024;  // + slot*16384 (+8192 rows 128..255)
    char* stDstB = Bs + wid * 1024;
    // Swizzled fragment-read lane offset: (l&15)*64 + ((l>>4)^((l>>1)&3))*16.
    const int lsw = (l & 15) * 64 + ((((l >> 4) ^ ((l >> 1) & 3))) * 16);
    const char* rdA = As + wm * 8192 + lsw;   // + slot*16384 + sub*1024
    const char* rdB = Bs + wn * 4096 + lsw;   // + slot*16384 + sub*1024

    // Prologue: stage halves 0 and 1 (8 loads in flight).
    STG(sA, stDstA, 0, 0)
    STG(sB, stDstB, 0, 0)
    STG(sA, stDstA, 64, 1)
    STG(sB, stDstB, 64, 1)

    int kb = 128;                    // byte offset of half 2
    for (int grp = 0; grp < 7; ++grp) {   // phases 0..27
        PH(0, true, kb, VMCNT(8))
        PH(1, true, kb + 64, VMCNT(8))
        PH(2, true, kb + 128, VMCNT(8))
        PH(3, true, kb + 192, VMCNT(8))
        kb += 256;
    }
    PH(0, true, 1920, VMCNT(8))      // g=28, stages half 30
    PH(1, true, 1984, VMCNT(8))      // g=29, stages half 31
    PH(2, false, 0, VMCNT(4))        // g=30 (drain stage 30)
    PH(3, false, 0, VMCNT(0))        // g=31 (drain stage 31)
}

// ---------------------------------------------------------------------------
// GEMM1 + fused head-mix epilogue on the 256x256 tile.  Columns
// (k,h)-interleaved; mix group = 8 consecutive cols.  NOW 4 passes x 64-row
// slab (64x264 f32 = 67.6KB, fits the freed 128KB K-loop LDS) -> 9 barriers
// instead of 17.
__global__ __launch_bounds__(512, 2) void gemm1_mix(
    const unsigned short* __restrict__ A, const unsigned short* __restrict__ B,
    const float* __restrict__ coef, const int* __restrict__ causal,
    unsigned short* __restrict__ C) {
    __shared__ char smem[131072];
    __shared__ float cfs[64];
    const int t = threadIdx.x;
    long rowBase, colBase;
    swz256(blockIdx.x, rowBase, colBase);
    const int b = (int)(rowBase >> 12);
    if (t < 64) cfs[t] = coef[b * 64 + t];
    const int causalv = causal[0];

    f32x4 acc[8][4] = {};
    gemm8_core((const char*)A + rowBase * 2048, (const char*)B + colBase * 2048,
               smem, t, acc);
    __syncthreads();                 // last phase's LDS reads vs slab writes

    const int l = t & 63, wid = t >> 6;
    const int wm = wid >> 2, wn = wid & 3;
    const int q = l >> 4, c16 = l & 15;
    float* slab = (float*)smem;      // 64 x 264 f32
#pragma unroll
    for (int p = 0; p < 4; ++p) {
        if (wm == (p >> 1)) {
            const int m0 = (p & 1) * 4;
#pragma unroll
            for (int m2 = 0; m2 < 4; ++m2)
#pragma unroll
                for (int ni = 0; ni < 4; ++ni)
#pragma unroll
                    for (int r = 0; r < 4; ++r)
                        slab[(m2 * 16 + q * 4 + r) * 264 + wn * 64 + ni * 16 + c16] =
                            acc[m0 + m2][ni][r];
        }
        __syncthreads();
#pragma unroll
        for (int gg = 0; gg < 4; ++gg) {
            const int g = t + gg * 512;          // 2048 = 64 rows x 32 kgroups
            const int row64 = g >> 5, kg = g & 31;
            const float* src = slab + row64 * 264 + kg * 8;
            float v[8];
#pragma unroll
            for (int j = 0; j < 8; ++j) v[j] = src[j];
            const long row = rowBase + p * 64 + row64;
            const float scale =
                causalv ? (float)((row & 4095) + 1) * (1.0f / 4096.0f) : 1.0f;
            us8 o;
#pragma unroll
            for (int i = 0; i < 8; ++i) {
                float ts = 0.f;
#pragma unroll
                for (int j = 0; j < 8; ++j) ts += cfs[i * 8 + j] * v[j];
                o[i] = f2bf(v[i] + scale * ts);
            }
            *(us8*)(C + row * 1024 + colBase + kg * 8) = o;
        }
        __syncthreads();
    }
}

// ---------------------------------------------------------------------------
// Plain GEMM (second projection): C = A @ B^T, bf16 out (r2-verified epilogue).
__global__ __launch_bounds__(512, 2) void gemm_bt(const unsigned short* __restrict__ A,
                                                  const unsigned short* __restrict__ B,
                                                  unsigned short* __restrict__ C) {
    __shared__ char smem[131072];
    const int t = threadIdx.x;
    long rowBase, colBase;
    swz256(blockIdx.x, rowBase, colBase);

    f32x4 acc[8][4] = {};
    gemm8_core((const char*)A + rowBase * 2048, (const char*)B + colBase * 2048,
               smem, t, acc);

    const int l = t & 63, wid = t >> 6;
    const int wm = wid >> 2, wn = wid & 3;
    const int q = l >> 4, c16 = l & 15;
#pragma unroll
    for (int mi = 0; mi < 8; ++mi)
#pragma unroll
        for (int ni = 0; ni < 4; ++ni) {
            const long col = colBase + wn * 64 + ni * 16 + c16;
            const long row0 = rowBase + wm * 128 + mi * 16 + q * 4;
#pragma unroll
            for (int r = 0; r < 4; ++r)
                C[(row0 + r) * 1024 + col] = f2bf(acc[mi][ni][r]);
        }
}

// ---------------------------------------------------------------------------
// LayerNorm over D=1024: y = ypre + out_b + x; out = (y-mu)/sqrt(var+eps)*g+b
__global__ __launch_bounds__(256) void ln_k(const unsigned short* __restrict__ ypre,
                                            const float* __restrict__ x,
                                            const float* __restrict__ outb,
                                            const float* __restrict__ gam,
                                            const float* __restrict__ bet,
                                            float* __restrict__ out) {
    int row = blockIdx.x;       // 16384
    int t = threadIdx.x;        // 256, 4 elems each
    long base = (long)row * 1024 + t * 4;
    ushort4 yp = *(const ushort4*)(ypre + base);
    float4 xv = *(const float4*)(x + base);
    float4 bv = *(const float4*)(outb + t * 4);
    float y0 = bf2f(yp.x) + xv.x + bv.x;
    float y1 = bf2f(yp.y) + xv.y + bv.y;
    float y2 = bf2f(yp.z) + xv.z + bv.z;
    float y3 = bf2f(yp.w) + xv.w + bv.w;
    float s = y0 + y1 + y2 + y3;
    float ss = y0 * y0 + y1 * y1 + y2 * y2 + y3 * y3;
    for (int off = 32; off; off >>= 1) {
        s += __shfl_down(s, off);
        ss += __shfl_down(ss, off);
    }
    __shared__ float red[8];
    int wv = t >> 6, ln = t & 63;
    if (ln == 0) { red[wv] = s; red[4 + wv] = ss; }
    __syncthreads();
    float S1 = red[0] + red[1] + red[2] + red[3];
    float S2 = red[4] + red[5] + red[6] + red[7];
    float mu = S1 * (1.0f / 1024.0f);
    float var = S2 * (1.0f / 1024.0f) - mu * mu;
    float rs = 1.0f / sqrtf(var + 1e-5f);
    float4 gv = *(const float4*)(gam + t * 4);
    float4 bb = *(const float4*)(bet + t * 4);
    float4 o;
    o.x = (y0 - mu) * rs * gv.x + bb.x;
    o.y = (y1 - mu) * rs * gv.y + bb.y;
    o.z = (y2 - mu) * rs * gv.z + bb.z;
    o.w = (y3 - mu) * rs * gv.w + bb.w;
    *(float4*)(out + base) = o;
}

// ---------------------------------------------------------------------------
extern "C" void kernel_launch(void* const* d_in, const int* in_sizes, int n_in,
                              void* d_out, int out_size, void* d_ws, size_t ws_size,
                              hipStream_t stream) {
    const float* x       = (const float*)d_in[0];
    const float* W_proj  = (const float*)d_in[1];
    const float* freqs   = (const float*)d_in[2];
    const float* pol_W   = (const float*)d_in[3];
    const float* pol_b   = (const float*)d_in[4];
    const float* imp_W1  = (const float*)d_in[5];
    const float* imp_b1  = (const float*)d_in[6];
    const float* imp_W2  = (const float*)d_in[7];
    const float* imp_b2  = (const float*)d_in[8];
    const float* out_W   = (const float*)d_in[9];
    const float* out_b   = (const float*)d_in[10];
    const float* ln_g    = (const float*)d_in[11];
    const float* ln_b    = (const float*)d_in[12];
    const int*   causal  = (const int*)d_in[13];
    float* out = (float*)d_out;

    char* ws = (char*)d_ws;
    unsigned short* xb      = (unsigned short*)(ws + 0);          // 32MB, reused as ypre
    unsigned short* merged  = (unsigned short*)(ws + 33554432);   // 32MB
    unsigned short* w1b     = (unsigned short*)(ws + 67108864);   // 2MB
    unsigned short* wob     = (unsigned short*)(ws + 69206016);   // 2MB
    float* xbar             = (float*)(ws + 71303168);            // 16KB
    float* summary          = (float*)(ws + 71319552);            // 16KB
    float* coef             = (float*)(ws + 71335936);            // 1KB
    float* part             = (float*)merged;                     // 4MB, dead before gemm1_mix
    unsigned short* ypre    = xb;

    prep_k<<<5120, 256, 0, stream>>>(W_proj, freqs, out_W, w1b, wob);
    xbar_cast<<<1024, 256, 0, stream>>>(x, xb, part);
    xbar_r<<<32, 256, 0, stream>>>(part, xbar);
    summary_k<<<1024, 256, 0, stream>>>(xbar, W_proj, freqs, summary);
    imp_k<<<1, 1024, 0, stream>>>(summary, pol_W, pol_b, imp_W1, imp_b1,
                                  imp_W2, imp_b2, coef, out + 16777216);
    gemm1_mix<<<256, 512, 0, stream>>>(xb, w1b, coef, causal, merged);
    gemm_bt<<<256, 512, 0, stream>>>(merged, wob, ypre);
    ln_k<<<16384, 256, 0, stream>>>(ypre, x, out_b, ln_g, ln_b, out);
}